// Round 7
// baseline (434.668 us; speedup 1.0000x reference)
//
#include <hip/hip_runtime.h>
#include <hip/hip_bf16.h>
#include <math.h>

// ---------------------------------------------------------------------------
// KGAT on MI355X.
//   N = 100000 entities, R = 12 relations, D = 64, E = 1e6 edges.
//   proj[k,n,r] = sum_d emb[n,d] * W_r[k,d,r]   -> bf16 MFMA GEMM (PLANE-major)
//   logits[e]   = sum_r proj[et,src,r] * tanh(proj[et,dst,r] + rel[et,r])
//   att         = edge_softmax(logits, by dst)  (unnormalized exp; logits bounded)
//   layer(x):   h = segsum(x[src]*att -> dst); y = lrelu((x+h)W1^T+b1)+lrelu((x*h)W2^T+b2)
//   out = [x0 | x1 | x2]  row stride 160 (f32)
// R14: projb1 was imbalance+epilogue-bound (905 blocks/256 CU = 3.5, 21% occ;
//     384 scalar ds_write_b16/wave with 4-way conflicts = the 600k counter).
//     (a) OPERAND-SWAP epilogue: mfma(A=W_r^T, B=emb) -> C row=comp,col=node;
//         lane holds 4 consecutive comps -> pack + global_store_dwordx2
//         direct. LDS tile/bounce deleted entirely.
//     (b) 64-node GEMM blocks: 1686 total blocks (6.6/CU), tail ~8%.
//     (c) degree-count (1e6 random atomics in prep) + blocksum/scan/binit
//         DELETED: bsort1 stages into per-bucket fixed-cap regions (cap =
//         1.5x mean + 1k, ~50 sigma); k_bscan (196 vals) -> bucket bases;
//         k_bsort2 local-histograms, scans, writes row_ptr AND places edges.
// ---------------------------------------------------------------------------

typedef __attribute__((ext_vector_type(8))) short short8;   // 8 bf16 (4 VGPR)
typedef __attribute__((ext_vector_type(4))) float float4v;  // MFMA acc

__device__ __forceinline__ short f2bf(float f) {
  __hip_bfloat16 h = __float2bfloat16(f);
  return *(short*)&h;
}
__device__ __forceinline__ float bf2f(short s) {
  return __uint_as_float(((unsigned)(unsigned short)s) << 16);
}
__device__ __forceinline__ unsigned packbf(float lo, float hi) {
  return (unsigned)(unsigned short)f2bf(lo) |
         ((unsigned)(unsigned short)f2bf(hi) << 16);
}

#define LOG2E 1.4426950408889634f

// Merged prep: [0,nb_cvt) emb f32->bf16 | 12 blocks W_r transpose+cvt |
// 48 blocks layer-weight hi/lo bf16 split. (Degree count DELETED: the bucket
// sort derives all offsets itself.)
__global__ void k_prep(const float* __restrict__ emb, short* __restrict__ emb_h,
                       const float* __restrict__ Wr, short* __restrict__ Bt,
                       const float* __restrict__ W10, const float* __restrict__ W20,
                       const float* __restrict__ W11, const float* __restrict__ W21,
                       short* __restrict__ w1h0, short* __restrict__ w1l0,
                       short* __restrict__ w2h0, short* __restrict__ w2l0,
                       short* __restrict__ w1h1, short* __restrict__ w1l1,
                       short* __restrict__ w2h1, short* __restrict__ w2l1,
                       int nb_cvt, int n4) {
  int b = blockIdx.x, t = threadIdx.x;
  if (b < nb_cvt) {
    int i = b * 256 + t;
    if (i < n4) {
      float4 v = ((const float4*)emb)[i];
      union { short s[4]; uint2 u; } o;
      o.s[0] = f2bf(v.x); o.s[1] = f2bf(v.y); o.s[2] = f2bf(v.z); o.s[3] = f2bf(v.w);
      ((uint2*)emb_h)[i] = o.u;
    }
  } else if (b < nb_cvt + 12) {
    int k = b - nb_cvt;
    for (int i = t; i < 4096; i += 256) {
      int d = i >> 6, r = i & 63;
      Bt[k * 4096 + r * 64 + d] = f2bf(Wr[k * 4096 + i]);
    }
  } else {
    int i = (b - nb_cvt - 12) * 256 + t;
    const float* W; short* H; short* L; int j;
    if (i < 4096) { W = W10; H = w1h0; L = w1l0; j = i; }
    else if (i < 8192) { W = W20; H = w2h0; L = w2l0; j = i - 4096; }
    else if (i < 10240) { W = W11; H = w1h1; L = w1l1; j = i - 8192; }
    else if (i < 12288) { W = W21; H = w2h1; L = w2l1; j = i - 10240; }
    else return;
    float w = W[j];
    short hi = f2bf(w);
    H[j] = hi;
    L[j] = f2bf(w - bf2f(hi));
  }
}

// Merged proj GEMM + bucket-sort pass B, INTERLEAVED (every K-th block is a
// bsort1 block; bijective index math). bsort1 latency hides under the GEMM.
// GEMM (operand-swapped): wave = 64 comps x 16 nodes per relation,
// mfma(A = W_r^T frags [comp][d], B = emb frags [node][d]) -> C row=comp,
// col=node. Lane (quad,l16) holds comps mt*16+quad*4+{0..3} of node
// n0+l16 -> pack 4 bf16 into uint2, store DIRECT to proj[k][node][comp]
// (8B/lane; 4-lane quad groups contiguous 32B). No LDS, no bounce.
// bsort1: 8192-edge tile, LDS hist over dst>>bsh buckets, one atomicAdd per
// (block,bucket) reserves a run in the bucket's fixed-cap staging region.
__global__ __launch_bounds__(256) void k_projb1(const short* __restrict__ A,
                                                const short* __restrict__ Bt,
                                                short* __restrict__ proj,
                                                int n_ent,
                                                const int* __restrict__ src,
                                                const int* __restrict__ dst,
                                                const int* __restrict__ et,
                                                int* __restrict__ bcur,
                                                uint2* __restrict__ stg,
                                                int nE, int bsh, int cap,
                                                int nb1, int K) {
  __shared__ int hist[256];
  __shared__ int base[256];
  int bid = blockIdx.x;
  int g = bid / K, p = bid - g * K;
  int t = threadIdx.x;
  if (p == 0 && g < nb1) {
    // ---- bsort1 block g ----
    hist[t] = 0;
    __syncthreads();
    int tile = g * 8192;
#pragma unroll 4
    for (int j = 0; j < 32; j++) {
      int e = tile + j * 256 + t;
      if (e < nE) atomicAdd(&hist[dst[e] >> bsh], 1);
    }
    __syncthreads();
    int cnt = hist[t];
    if (cnt > 0) base[t] = atomicAdd(&bcur[t], cnt);  // staging offset in bucket t
    hist[t] = 0;  // reuse as intra-block rank counter
    __syncthreads();
#pragma unroll 4
    for (int j = 0; j < 32; j++) {
      int e = tile + j * 256 + t;
      if (e < nE) {
        int d = dst[e], bk = d >> bsh;
        int r = atomicAdd(&hist[bk], 1);
        stg[(size_t)bk * cap + base[bk] + r] =
            make_uint2((unsigned)src[e], (unsigned)d | ((unsigned)et[e] << 20));
      }
    }
    return;
  }
  int npre = g + (p > 0 ? 1 : 0);
  if (npre > nb1) npre = nb1;
  int gb = bid - npre;  // GEMM block index
  int wave = t >> 6, lane = t & 63;
  int quad = lane >> 4, l16 = lane & 15;
  int n0 = gb * 64 + wave * 16;  // 16 nodes per wave
  int node = n0 + l16;
  int rr = node < n_ent ? node : 0;  // clamp; clamped nodes never stored
  short8 bfrag[2];
#pragma unroll
  for (int kc = 0; kc < 2; kc++)
    bfrag[kc] = *(const short8*)(A + (size_t)rr * 64 + kc * 32 + quad * 8);
  for (int k = 0; k < 12; k++) {
    const short* B = Bt + k * 4096;
    short8 af[4][2];
#pragma unroll
    for (int mt = 0; mt < 4; mt++)
#pragma unroll
      for (int kc = 0; kc < 2; kc++)
        af[mt][kc] = *(const short8*)(B + (mt * 16 + l16) * 64 + kc * 32 + quad * 8);
    float4v acc[4];
#pragma unroll
    for (int mt = 0; mt < 4; mt++) acc[mt] = (float4v){0.f, 0.f, 0.f, 0.f};
#pragma unroll
    for (int kc = 0; kc < 2; kc++)
#pragma unroll
      for (int mt = 0; mt < 4; mt++)
        acc[mt] = __builtin_amdgcn_mfma_f32_16x16x32_bf16(
            af[mt][kc], bfrag[kc], acc[mt], 0, 0, 0);
    // C: col(l16)=node, row=comp mt*16+quad*4+r -> 4 consecutive comps/lane
    if (node < n_ent) {
      short* pr = proj + ((size_t)k * n_ent + node) * 64;
#pragma unroll
      for (int mt = 0; mt < 4; mt++) {
        uint2 pk = make_uint2(packbf(acc[mt][0], acc[mt][1]),
                              packbf(acc[mt][2], acc[mt][3]));
        *(uint2*)(pr + mt * 16 + quad * 4) = pk;
      }
    }
  }
}

// Tiny scan over bucket counts -> bucket bases in final CSR.
__global__ void k_bscan(const int* __restrict__ bcur, int* __restrict__ bbase,
                        int* __restrict__ row_ptr, int nbuck, int n, int nE) {
  __shared__ int s[256];
  int t = threadIdx.x;
  int v = (t < nbuck) ? bcur[t] : 0;
  s[t] = v;
  __syncthreads();
  for (int o = 1; o < 256; o <<= 1) {
    int a = (t >= o) ? s[t - o] : 0;
    __syncthreads();
    s[t] += a;
    __syncthreads();
  }
  if (t < nbuck) bbase[t] = s[t] - v;  // exclusive
  if (t == 0) row_ptr[n] = nE;
}

// Bucket-sort pass C: one block per bucket. Local LDS histogram over its
// <=1024 dsts, local scan -> per-dst offsets; writes row_ptr AND places
// edges. Output region block-exclusive -> full write combining.
__global__ __launch_bounds__(256) void k_bsort2(const uint2* __restrict__ stg,
                                                const int* __restrict__ bcur,
                                                const int* __restrict__ bbase,
                                                int* __restrict__ row_ptr,
                                                uint2* __restrict__ csr2,
                                                int n, int bsh, int cap) {
  __shared__ int cnt[1024];
  __shared__ int sc[1024];
  int b = blockIdx.x, t = threadIdx.x;
  int lo = b << bsh;
  if (lo > n) lo = n;
  int hi = (b + 1) << bsh;
  if (hi > n) hi = n;
  int w = hi - lo;
#pragma unroll
  for (int j = 0; j < 4; j++) cnt[t + j * 256] = 0;
  __syncthreads();
  int m = bcur[b];
  const uint2* S = stg + (size_t)b * cap;
  for (int p = t; p < m; p += 256)
    atomicAdd(&cnt[(int)(S[p].y & 0xFFFFFu) - lo], 1);
  __syncthreads();
#pragma unroll
  for (int j = 0; j < 4; j++) sc[t + j * 256] = cnt[t + j * 256];
  __syncthreads();
  for (int o = 1; o < 1024; o <<= 1) {
    int a[4];
#pragma unroll
    for (int j = 0; j < 4; j++) {
      int i = t + j * 256;
      a[j] = (i >= o) ? sc[i - o] : 0;
    }
    __syncthreads();
#pragma unroll
    for (int j = 0; j < 4; j++) sc[t + j * 256] += a[j];
    __syncthreads();
  }
  int gbase = bbase[b];
#pragma unroll
  for (int j = 0; j < 4; j++) {
    int i = t + j * 256;
    if (i < w) {
      int c0 = gbase + sc[i] - cnt[i];  // exclusive offset for dst lo+i
      row_ptr[lo + i] = c0;
      cnt[i] = c0;  // reuse as global cursor
    }
  }
  __syncthreads();
  for (int p = t; p < m; p += 256) {
    uint2 v = S[p];
    int d = (int)(v.y & 0xFFFFFu);
    int pos = atomicAdd(&cnt[d - lo], 1);
    csr2[pos] = v;
  }
}

// Edge scores + exp, walking edges in dst-sorted order (csr2): head gathers
// stream monotonically through each proj plane, tail gathers hit LLC behind
// the stream. ex is written IN PLACE over csr2[e].y. 8 lanes per edge
// (128B rows), 4 edge-batches per wave. proj is PLANE-major [k][N][64].
__global__ __launch_bounds__(256) void k_logits(const short* __restrict__ ps,
                                                const float* __restrict__ rel_emb,
                                                uint2* csr2, int nE, int n_ent) {
  int t = threadIdx.x;
  int lane = t & 63;
  int sub = lane >> 3;        // edge slot within wave (0..7)
  int c8 = (lane & 7) * 8;    // component group base
  int e0 = (blockIdx.x * 4 + (t >> 6)) * 32;
  if (e0 >= nE) return;
  int ku[4];
  short8 tl[4], hd[4];
#pragma unroll
  for (int u = 0; u < 4; u++) {
    int e = e0 + u * 8 + sub;
    int ee = e < nE ? e : nE - 1;
    uint2 c = csr2[ee];
    int s = (int)c.x;
    int d = (int)(c.y & 0xFFFFFu);
    int k = (int)(c.y >> 20);
    ku[u] = k;
    const size_t plane = (size_t)k * n_ent;
    tl[u] = *(const short8*)(ps + (plane + s) * 64 + c8);
    hd[u] = *(const short8*)(ps + (plane + d) * 64 + c8);
  }
  float v[4];
#pragma unroll
  for (int u = 0; u < 4; u++) {
    const float* rp = rel_emb + ku[u] * 64 + c8;
    float4 r0 = *(const float4*)rp;
    float4 r1 = *(const float4*)(rp + 4);
    float rr[8] = {r0.x, r0.y, r0.z, r0.w, r1.x, r1.y, r1.z, r1.w};
    float vv = 0.f;
#pragma unroll
    for (int q = 0; q < 8; q++) {
      float x = bf2f(hd[u][q]) + rr[q];
      // tanh(x) = 1 - 2/(exp2(2*log2e*x)+1); v_exp + v_rcp, no IEEE div
      float tt = __builtin_amdgcn_exp2f(x * (2.f * LOG2E));
      float r = __builtin_amdgcn_rcpf(tt + 1.f);
      float th = fmaf(-2.f, r, 1.f);
      vv = fmaf(bf2f(tl[u][q]), th, vv);
    }
    vv += __shfl_xor(vv, 1);
    vv += __shfl_xor(vv, 2);
    vv += __shfl_xor(vv, 4);
    v[u] = __builtin_amdgcn_exp2f(vv * LOG2E);  // e^vv; logits bounded
  }
  // One edge per lane (32 lanes): edge (u=lane&7, sub). v is uniform across
  // each sub-group of 8 lanes, so the select chain is safe.
  int uu = lane & 7;
  if (uu < 4) {
    float myv = v[0];
    if (uu == 1) myv = v[1];
    if (uu == 2) myv = v[2];
    if (uu == 3) myv = v[3];
    int e = e0 + uu * 8 + sub;
    if (e < nE) csr2[e].y = __float_as_uint(myv);
  }
}

// h_n[n,:] = (sum_j ex_j * x[src_j,:]) / den. Wave per node, lane = col.
// ONE coalesced csr load (lane=entry), shfl broadcast, den wave-reduced.
// Masked 8-wide batches: lanes >= deg hold exv=0 so OOR shfl sources add 0.
__global__ __launch_bounds__(256) void k_agg(const short* __restrict__ xh,
                                             const int* __restrict__ row_ptr,
                                             const uint2* __restrict__ csr,
                                             float* __restrict__ hn, int n_ent) {
  int wave = threadIdx.x >> 6, lane = threadIdx.x & 63;
  int n = blockIdx.x * 4 + wave;
  if (n >= n_ent) return;
  int jb = row_ptr[n], je = row_ptr[n + 1];
  int deg = je - jb;
  if (deg == 0) {
    hn[(size_t)n * 64 + lane] = 0.f;  // no edges: reference h = 0
    return;
  }
  uint2 c = (lane < deg) ? csr[jb + lane] : make_uint2(0u, 0u);
  int sidx = (int)c.x;
  float exv = (lane < deg) ? __uint_as_float(c.y) : 0.f;
  float den = exv;
#pragma unroll
  for (int o = 32; o; o >>= 1) den += __shfl_xor(den, o);
  int m = deg < 64 ? deg : 64;
  float acc = 0.f;
  for (int j = 0; j < m; j += 8) {
    int s0 = __shfl(sidx, j), s1 = __shfl(sidx, j + 1);
    int s2 = __shfl(sidx, j + 2), s3 = __shfl(sidx, j + 3);
    int s4 = __shfl(sidx, j + 4), s5 = __shfl(sidx, j + 5);
    int s6 = __shfl(sidx, j + 6), s7 = __shfl(sidx, j + 7);
    float e0 = __shfl(exv, j), e1 = __shfl(exv, j + 1);
    float e2 = __shfl(exv, j + 2), e3 = __shfl(exv, j + 3);
    float e4 = __shfl(exv, j + 4), e5 = __shfl(exv, j + 5);
    float e6 = __shfl(exv, j + 6), e7 = __shfl(exv, j + 7);
    short g0 = xh[(size_t)s0 * 64 + lane];
    short g1 = xh[(size_t)s1 * 64 + lane];
    short g2 = xh[(size_t)s2 * 64 + lane];
    short g3 = xh[(size_t)s3 * 64 + lane];
    short g4 = xh[(size_t)s4 * 64 + lane];
    short g5 = xh[(size_t)s5 * 64 + lane];
    short g6 = xh[(size_t)s6 * 64 + lane];
    short g7 = xh[(size_t)s7 * 64 + lane];
    acc = fmaf(e0, bf2f(g0), acc); acc = fmaf(e1, bf2f(g1), acc);
    acc = fmaf(e2, bf2f(g2), acc); acc = fmaf(e3, bf2f(g3), acc);
    acc = fmaf(e4, bf2f(g4), acc); acc = fmaf(e5, bf2f(g5), acc);
    acc = fmaf(e6, bf2f(g6), acc); acc = fmaf(e7, bf2f(g7), acc);
  }
  if (deg > 64) {  // rare (E/N ~ 10); broadcast loads, den stays uniform
    for (int jj = jb + 64; jj < je; jj++) {
      uint2 cc = csr[jj];
      float ee = __uint_as_float(cc.y);
      den += ee;
      acc = fmaf(ee, bf2f(xh[(size_t)cc.x * 64 + lane]), acc);
    }
  }
  hn[(size_t)n * 64 + lane] = acc / den;
}

// y = lrelu((x+h)W1^T+b1) + lrelu((x*h)W2^T+b2) via MFMA.
// Split-bf16 GEMM (3 terms) keeps f32-level accuracy. Block = 4 waves x 32
// nodes = 128 nodes. Weights (hi/lo) staged once to LDS, stride 72 shorts
// (16B-aligned rows, bank-uniform ds_read_b128). A fragments built from f32
// x/hn loads. FIRST also emits x0 passthrough, x1 f32 and x1 bf16.
template <int OD, bool FIRST>
__global__ __launch_bounds__(256) void k_upmfma(const float* __restrict__ x,
                                                const float* __restrict__ hn,
                                                const short* __restrict__ g1h,
                                                const short* __restrict__ g1l,
                                                const short* __restrict__ g2h,
                                                const short* __restrict__ g2l,
                                                const float* __restrict__ b1,
                                                const float* __restrict__ b2,
                                                float* __restrict__ out,
                                                float* __restrict__ x_next,
                                                short* __restrict__ xh_next,
                                                int n_ent) {
  constexpr int NT = OD / 16;
  __shared__ short w1h[OD * 72], w1l[OD * 72], w2h[OD * 72], w2l[OD * 72];
  int t = threadIdx.x;
  for (int i = t; i < OD * 16; i += 256) {  // uint2 = 4 shorts per slot
    int o = i >> 4, dq = (i & 15) * 4;
    *(uint2*)(w1h + o * 72 + dq) = *(const uint2*)(g1h + o * 64 + dq);
    *(uint2*)(w1l + o * 72 + dq) = *(const uint2*)(g1l + o * 64 + dq);
    *(uint2*)(w2h + o * 72 + dq) = *(const uint2*)(g2h + o * 64 + dq);
    *(uint2*)(w2l + o * 72 + dq) = *(const uint2*)(g2l + o * 64 + dq);
  }
  int wave = t >> 6, lane = t & 63;
  int quad = lane >> 4, l16 = lane & 15;
  int m0 = blockIdx.x * 128 + wave * 32;
  float4v accA[2][NT], accM[2][NT];
#pragma unroll
  for (int mt = 0; mt < 2; mt++)
#pragma unroll
    for (int nt = 0; nt < NT; nt++) {
      accA[mt][nt] = (float4v){0.f, 0.f, 0.f, 0.f};
      accM[mt][nt] = (float4v){0.f, 0.f, 0.f, 0.f};
    }
  __syncthreads();
#pragma unroll
  for (int kc = 0; kc < 2; kc++) {
    short8 ah_add[2], al_add[2], ah_mul[2], al_mul[2];
#pragma unroll
    for (int mt = 0; mt < 2; mt++) {
      int row = m0 + mt * 16 + l16;
      int rr = row < n_ent ? row : 0;  // clamp; clamped rows never stored
      const float* xp = x + (size_t)rr * 64 + kc * 32 + quad * 8;
      const float* hp = hn + (size_t)rr * 64 + kc * 32 + quad * 8;
      float4 xa = *(const float4*)xp;
      float4 xb = *(const float4*)(xp + 4);
      float4 ha = *(const float4*)hp;
      float4 hb = *(const float4*)(hp + 4);
      if (FIRST && row < n_ent) {  // x0 passthrough from the same loads
        *(float4*)(out + (size_t)row * 160 + kc * 32 + quad * 8) = xa;
        *(float4*)(out + (size_t)row * 160 + kc * 32 + quad * 8 + 4) = xb;
      }
      float xs[8] = {xa.x, xa.y, xa.z, xa.w, xb.x, xb.y, xb.z, xb.w};
      float hs[8] = {ha.x, ha.y, ha.z, ha.w, hb.x, hb.y, hb.z, hb.w};
#pragma unroll
      for (int q = 0; q < 8; q++) {
        float s = xs[q] + hs[q];
        short shi = f2bf(s);
        ah_add[mt][q] = shi;
        al_add[mt][q] = f2bf(s - bf2f(shi));
        float p = xs[q] * hs[q];
        short phi = f2bf(p);
        ah_mul[mt][q] = phi;
        al_mul[mt][q] = f2bf(p - bf2f(phi));
      }
    }
#pragma unroll
    for (int nt = 0; nt < NT; nt++) {
      int boff = (nt * 16 + l16) * 72 + kc * 32 + quad * 8;
      short8 b1h = *(const short8*)(w1h + boff);
      short8 b1l = *(const short8*)(w1l + boff);
      short8 b2h = *(const short8*)(w2h + boff);
      short8 b2l = *(const short8*)(w2l + boff);
#pragma unroll
      for (int mt = 0; mt < 2; mt++) {
        accA[mt][nt] = __builtin_amdgcn_mfma_f32_16x16x32_bf16(
            ah_add[mt], b1h, accA[mt][nt], 0, 0, 0);
        accA[mt][nt] = __builtin_amdgcn_mfma_f32_16x16x32_bf16(
            al_add[mt], b1h, accA[mt][nt], 0, 0, 0);
        accA[mt][nt] = __builtin_amdgcn_mfma_f32_16x16x32_bf16(
            ah_add[mt], b1l, accA[mt][nt], 0, 0, 0);
        accM[mt][nt] = __builtin_amdgcn_mfma_f32_16x16x32_bf16(
            ah_mul[mt], b2h, accM[mt][nt], 0, 0, 0);
        accM[mt][nt] = __builtin_amdgcn_mfma_f32_16x16x32_bf16(
            al_mul[mt], b2h, accM[mt][nt], 0, 0, 0);
        accM[mt][nt] = __builtin_amdgcn_mfma_f32_16x16x32_bf16(
            ah_mul[mt], b2l, accM[mt][nt], 0, 0, 0);
      }
    }
  }
  // C layout: col = nt*16+l16, row = mt*16 + quad*4 + r
#pragma unroll
  for (int nt = 0; nt < NT; nt++) {
    int col = nt * 16 + l16;
    float bb1 = b1[col], bb2 = b2[col];
#pragma unroll
    for (int mt = 0; mt < 2; mt++) {
#pragma unroll
      for (int r = 0; r < 4; r++) {
        int row = m0 + mt * 16 + quad * 4 + r;
        float aa = accA[mt][nt][r] + bb1;
        float mm = accM[mt][nt][r] + bb2;
        aa = aa > 0.f ? aa : 0.01f * aa;
        mm = mm > 0.f ? mm : 0.01f * mm;
        float y = aa + mm;
        if constexpr (FIRST) {
          float yn = __shfl_xor(y, 1);  // partner col^1, same row (quad equal)
          if (row < n_ent) {
            out[(size_t)row * 160 + 64 + col] = y;
            x_next[(size_t)row * 64 + col] = y;
            if ((lane & 1) == 0) {
              unsigned pk = (unsigned)(unsigned short)f2bf(y) |
                            ((unsigned)(unsigned short)f2bf(yn) << 16);
              *(unsigned*)(xh_next + (size_t)row * 64 + col) = pk;
            }
          }
        } else {
          if (row < n_ent) out[(size_t)row * 160 + 128 + col] = y;
        }
      }
    }
  }
}

extern "C" void kernel_launch(void* const* d_in, const int* in_sizes, int n_in,
                              void* d_out, int out_size, void* d_ws, size_t ws_size,
                              hipStream_t stream) {
  const float* emb = (const float*)d_in[0];
  const float* rel = (const float*)d_in[1];
  const float* Wr = (const float*)d_in[2];
  const float* W10w = (const float*)d_in[3];
  const float* W10b = (const float*)d_in[4];
  const float* W20w = (const float*)d_in[5];
  const float* W20b = (const float*)d_in[6];
  const float* W11w = (const float*)d_in[7];
  const float* W11b = (const float*)d_in[8];
  const float* W21w = (const float*)d_in[9];
  const float* W21b = (const float*)d_in[10];
  const int* src = (const int*)d_in[11];
  const int* dst = (const int*)d_in[12];
  const int* et = (const int*)d_in[13];
  int N = in_sizes[0] / 64;
  int E = in_sizes[11];
  float* out = (float*)d_out;

  int bsh = 9;
  while (((N + (1 << bsh) - 1) >> bsh) > 256) bsh++;  // nbuck <= 256
  int nbuck = (N + (1 << bsh) - 1) >> bsh;
  int cap = ((E / nbuck) * 3 / 2 + 1024 + 255) / 256 * 256;  // ~50 sigma margin

  char* p = (char*)d_ws;
  auto alloc = [&](size_t bytes) -> char* {
    char* r = p;
    p += (bytes + 255) / 256 * 256;
    return r;
  };
  short* proj = (short*)alloc((size_t)N * 768 * 2);
  uint2* csr2 = (uint2*)alloc((size_t)E * 8);  // final CSR {src, dst|et} -> {src, ex}
  uint2* stg = (uint2*)alloc((size_t)nbuck * cap * 8);  // per-bucket staging
  int* row_ptr = (int*)alloc((size_t)(N + 1) * 4);
  int* bcur = (int*)alloc(1024);               // bucket staging cursors
  int* bbase = (int*)alloc(2048);              // bucket bases in CSR
  float* hn = (float*)alloc((size_t)N * 64 * 4);
  float* x1 = (float*)alloc((size_t)N * 64 * 4);
  short* emb_h = (short*)alloc(((size_t)N + 128) * 64 * 2);  // bf16 emb, padded
  short* x1h = (short*)alloc(((size_t)N + 128) * 64 * 2);    // bf16 x1
  short* Bt = (short*)alloc((size_t)12 * 4096 * 2);          // bf16 W_r^T
  short* w1h0 = (short*)alloc(4096 * 2);                     // layer-weight hi/lo
  short* w1l0 = (short*)alloc(4096 * 2);
  short* w2h0 = (short*)alloc(4096 * 2);
  short* w2l0 = (short*)alloc(4096 * 2);
  short* w1h1 = (short*)alloc(2048 * 2);
  short* w1l1 = (short*)alloc(2048 * 2);
  short* w2h1 = (short*)alloc(2048 * 2);
  short* w2l1 = (short*)alloc(2048 * 2);

  int n4 = N * 16;
  int nb_cvt = (n4 + 255) / 256;
  int nb1 = (E + 8191) / 8192;       // bsort1 blocks
  int nb_gemm = (N + 63) / 64;       // GEMM blocks (64 nodes each)
  int nb_tot = nb1 + nb_gemm;
  int K = nb_tot / nb1;              // every K-th block is bsort1
  if (K < 1) K = 1;

  hipMemsetAsync(bcur, 0, 1024, stream);
  k_prep<<<nb_cvt + 60, 256, 0, stream>>>(
      emb, emb_h, Wr, Bt, W10w, W20w, W11w, W21w,
      w1h0, w1l0, w2h0, w2l0, w1h1, w1l1, w2h1, w2l1, nb_cvt, n4);
  k_projb1<<<nb_tot, 256, 0, stream>>>(
      emb_h, Bt, proj, N, src, dst, et, bcur, stg, E, bsh, cap, nb1, K);
  k_bscan<<<1, 256, 0, stream>>>(bcur, bbase, row_ptr, nbuck, N, E);
  k_bsort2<<<nbuck, 256, 0, stream>>>(stg, bcur, bbase, row_ptr, csr2, N, bsh, cap);
  k_logits<<<(E + 127) / 128, 256, 0, stream>>>(proj, rel, csr2, E, N);
  k_agg<<<(N + 3) / 4, 256, 0, stream>>>(emb_h, row_ptr, csr2, hn, N);
  k_upmfma<64, true><<<(N + 127) / 128, 256, 0, stream>>>(
      emb, hn, w1h0, w1l0, w2h0, w2l0, W10b, W20b, out, x1, x1h, N);
  k_agg<<<(N + 3) / 4, 256, 0, stream>>>(x1h, row_ptr, csr2, hn, N);
  k_upmfma<32, false><<<(N + 127) / 128, 256, 0, stream>>>(
      x1, hn, w1h1, w1l1, w2h1, w2l1, W11b, W21b, out, nullptr, nullptr, N);
}

// Round 8
// 406.240 us; speedup vs baseline: 1.0700x; 1.0700x over previous
//
#include <hip/hip_runtime.h>
#include <hip/hip_bf16.h>
#include <math.h>

// ---------------------------------------------------------------------------
// KGAT on MI355X.
//   N = 100000 entities, R = 12 relations, D = 64, E = 1e6 edges.
//   proj[k,n,r] = sum_d emb[n,d] * W_r[k,d,r]   -> bf16 MFMA GEMM (PLANE-major)
//   logits[e]   = sum_r proj[et,src,r] * tanh(proj[et,dst,r] + rel[et,r])
//   att         = edge_softmax(logits, by dst)  (unnormalized exp; logits bounded)
//   layer(x):   h = segsum(x[src]*att -> dst); y = lrelu((x+h)W1^T+b1)+lrelu((x*h)W2^T+b2)
//   out = [x0 | x1 | x2]  row stride 160 (f32)
// R15: R14's operand-swap direct-store epilogue REGRESSED (86->133us): 8B
//     per-lane stores fragment each wave-store into 16x32B segments (vs 1KB
//     contiguous via LDS bounce) -> write-request-throughput bound at 1.34
//     TB/s. Reverted GEMM to the R13-verified form (non-swapped mfma,
//     128-node blocks, LDS tile stride 72, short8 1KB stores, plane-major,
//     interleaved bsort1 = 86us measured). KEPT R14's sort simplification
//     (no degree atomics in prep; fixed-cap bucket staging; bscan; bsort2
//     writes row_ptr) which deletes 4 dispatches + 1e6 random atomics.
// ---------------------------------------------------------------------------

typedef __attribute__((ext_vector_type(8))) short short8;   // 8 bf16 (4 VGPR)
typedef __attribute__((ext_vector_type(4))) float float4v;  // MFMA acc

__device__ __forceinline__ short f2bf(float f) {
  __hip_bfloat16 h = __float2bfloat16(f);
  return *(short*)&h;
}
__device__ __forceinline__ float bf2f(short s) {
  return __uint_as_float(((unsigned)(unsigned short)s) << 16);
}

#define LOG2E 1.4426950408889634f

// Merged prep: [0,nb_cvt) emb f32->bf16 | 12 blocks W_r transpose+cvt |
// 48 blocks layer-weight hi/lo bf16 split. (No degree count: the bucket
// sort derives all offsets itself.)
__global__ void k_prep(const float* __restrict__ emb, short* __restrict__ emb_h,
                       const float* __restrict__ Wr, short* __restrict__ Bt,
                       const float* __restrict__ W10, const float* __restrict__ W20,
                       const float* __restrict__ W11, const float* __restrict__ W21,
                       short* __restrict__ w1h0, short* __restrict__ w1l0,
                       short* __restrict__ w2h0, short* __restrict__ w2l0,
                       short* __restrict__ w1h1, short* __restrict__ w1l1,
                       short* __restrict__ w2h1, short* __restrict__ w2l1,
                       int nb_cvt, int n4) {
  int b = blockIdx.x, t = threadIdx.x;
  if (b < nb_cvt) {
    int i = b * 256 + t;
    if (i < n4) {
      float4 v = ((const float4*)emb)[i];
      union { short s[4]; uint2 u; } o;
      o.s[0] = f2bf(v.x); o.s[1] = f2bf(v.y); o.s[2] = f2bf(v.z); o.s[3] = f2bf(v.w);
      ((uint2*)emb_h)[i] = o.u;
    }
  } else if (b < nb_cvt + 12) {
    int k = b - nb_cvt;
    for (int i = t; i < 4096; i += 256) {
      int d = i >> 6, r = i & 63;
      Bt[k * 4096 + r * 64 + d] = f2bf(Wr[k * 4096 + i]);
    }
  } else {
    int i = (b - nb_cvt - 12) * 256 + t;
    const float* W; short* H; short* L; int j;
    if (i < 4096) { W = W10; H = w1h0; L = w1l0; j = i; }
    else if (i < 8192) { W = W20; H = w2h0; L = w2l0; j = i - 4096; }
    else if (i < 10240) { W = W11; H = w1h1; L = w1l1; j = i - 8192; }
    else if (i < 12288) { W = W21; H = w2h1; L = w2l1; j = i - 10240; }
    else return;
    float w = W[j];
    short hi = f2bf(w);
    H[j] = hi;
    L[j] = f2bf(w - bf2f(hi));
  }
}

// Merged proj GEMM + bucket-sort pass B, INTERLEAVED (every K-th block is a
// bsort1 block; bijective index math). bsort1 latency hides under the GEMM.
// GEMM (R13-verified): wave = 32 rows x 64 cols per relation, 16x16x32 bf16
// MFMA. proj is PLANE-major [k][N][64]: per-block per-k store = 16KB
// contiguous. Epilogue bounces C through a WAVE-PRIVATE LDS tile (stride 72
// shorts) -> short8 1KB-contiguous stores. No barriers: intra-wave DS ops
// are in-order.
// bsort1: 8192-edge tile, LDS hist over dst>>bsh buckets, one atomicAdd per
// (block,bucket) reserves a run in the bucket's fixed-cap staging region.
__global__ __launch_bounds__(256) void k_projb1(const short* __restrict__ A,
                                                const short* __restrict__ Bt,
                                                short* __restrict__ proj,
                                                int n_ent,
                                                const int* __restrict__ src,
                                                const int* __restrict__ dst,
                                                const int* __restrict__ et,
                                                int* __restrict__ bcur,
                                                uint2* __restrict__ stg,
                                                int nE, int bsh, int cap,
                                                int nb1, int K) {
  __shared__ unsigned short sh[4][32 * 72];
  int bid = blockIdx.x;
  int g = bid / K, p = bid - g * K;
  int t = threadIdx.x;
  if (p == 0 && g < nb1) {
    // ---- bsort1 block g ----
    int* hist = (int*)&sh[0][0];
    int* base = hist + 256;
    hist[t] = 0;
    __syncthreads();
    int tile = g * 8192;
#pragma unroll 4
    for (int j = 0; j < 32; j++) {
      int e = tile + j * 256 + t;
      if (e < nE) atomicAdd(&hist[dst[e] >> bsh], 1);
    }
    __syncthreads();
    int cnt = hist[t];
    if (cnt > 0) base[t] = atomicAdd(&bcur[t], cnt);  // staging offset, bucket t
    hist[t] = 0;  // reuse as intra-block rank counter
    __syncthreads();
#pragma unroll 4
    for (int j = 0; j < 32; j++) {
      int e = tile + j * 256 + t;
      if (e < nE) {
        int d = dst[e], bk = d >> bsh;
        int r = atomicAdd(&hist[bk], 1);
        stg[(size_t)bk * cap + base[bk] + r] =
            make_uint2((unsigned)src[e], (unsigned)d | ((unsigned)et[e] << 20));
      }
    }
    return;
  }
  int npre = g + (p > 0 ? 1 : 0);
  if (npre > nb1) npre = nb1;
  int gb = bid - npre;  // GEMM block index
  int wave = t >> 6, lane = t & 63;
  int quad = lane >> 4, l16 = lane & 15;
  int m0 = gb * 128 + wave * 32;
  unsigned short* W = &sh[wave][0];
  short8 a[2][2];
#pragma unroll
  for (int mt = 0; mt < 2; mt++)
#pragma unroll
    for (int kc = 0; kc < 2; kc++) {
      int row = m0 + mt * 16 + l16;
      int rr = row < n_ent ? row : 0;  // clamp; clamped rows never stored
      a[mt][kc] = *(const short8*)(A + (size_t)rr * 64 + kc * 32 + quad * 8);
    }
  for (int k = 0; k < 12; k++) {
    const short* B = Bt + k * 4096;
    short8 b[4][2];
#pragma unroll
    for (int nt = 0; nt < 4; nt++)
#pragma unroll
      for (int kc = 0; kc < 2; kc++)
        b[nt][kc] = *(const short8*)(B + (nt * 16 + l16) * 64 + kc * 32 + quad * 8);
    float4v acc[2][4];
#pragma unroll
    for (int mt = 0; mt < 2; mt++)
#pragma unroll
      for (int nt = 0; nt < 4; nt++)
        acc[mt][nt] = (float4v){0.f, 0.f, 0.f, 0.f};
#pragma unroll
    for (int kc = 0; kc < 2; kc++)
#pragma unroll
      for (int mt = 0; mt < 2; mt++)
#pragma unroll
        for (int nt = 0; nt < 4; nt++)
          acc[mt][nt] = __builtin_amdgcn_mfma_f32_16x16x32_bf16(
              a[mt][kc], b[nt][kc], acc[mt][nt], 0, 0, 0);
    // C layout: col = nt*16+l16, row = mt*16 + quad*4 + r
#pragma unroll
    for (int mt = 0; mt < 2; mt++)
#pragma unroll
      for (int nt = 0; nt < 4; nt++)
#pragma unroll
        for (int r = 0; r < 4; r++) {
          int row = mt * 16 + quad * 4 + r;
          int col = nt * 16 + l16;
          W[row * 72 + col] = (unsigned short)f2bf(acc[mt][nt][r]);
        }
    const size_t plane = (size_t)k * n_ent;
#pragma unroll
    for (int i = 0; i < 4; i++) {
      int row = (lane >> 3) + 8 * i;
      int cs = (lane & 7) * 8;
      short8 v = *(const short8*)(W + row * 72 + cs);
      int node = m0 + row;
      if (node < n_ent)
        *(short8*)(proj + (plane + node) * 64 + cs) = v;
    }
  }
}

// Tiny scan over bucket counts -> bucket bases in final CSR.
__global__ void k_bscan(const int* __restrict__ bcur, int* __restrict__ bbase,
                        int* __restrict__ row_ptr, int nbuck, int n, int nE) {
  __shared__ int s[256];
  int t = threadIdx.x;
  int v = (t < nbuck) ? bcur[t] : 0;
  s[t] = v;
  __syncthreads();
  for (int o = 1; o < 256; o <<= 1) {
    int a = (t >= o) ? s[t - o] : 0;
    __syncthreads();
    s[t] += a;
    __syncthreads();
  }
  if (t < nbuck) bbase[t] = s[t] - v;  // exclusive
  if (t == 0) row_ptr[n] = nE;
}

// Bucket-sort pass C: one block per bucket. Local LDS histogram over its
// <=1024 dsts, local scan -> per-dst offsets; writes row_ptr AND places
// edges. Output region block-exclusive -> full write combining.
__global__ __launch_bounds__(256) void k_bsort2(const uint2* __restrict__ stg,
                                                const int* __restrict__ bcur,
                                                const int* __restrict__ bbase,
                                                int* __restrict__ row_ptr,
                                                uint2* __restrict__ csr2,
                                                int n, int bsh, int cap) {
  __shared__ int cnt[1024];
  __shared__ int sc[1024];
  int b = blockIdx.x, t = threadIdx.x;
  int lo = b << bsh;
  if (lo > n) lo = n;
  int hi = (b + 1) << bsh;
  if (hi > n) hi = n;
  int w = hi - lo;
#pragma unroll
  for (int j = 0; j < 4; j++) cnt[t + j * 256] = 0;
  __syncthreads();
  int m = bcur[b];
  const uint2* S = stg + (size_t)b * cap;
  for (int p = t; p < m; p += 256)
    atomicAdd(&cnt[(int)(S[p].y & 0xFFFFFu) - lo], 1);
  __syncthreads();
#pragma unroll
  for (int j = 0; j < 4; j++) sc[t + j * 256] = cnt[t + j * 256];
  __syncthreads();
  for (int o = 1; o < 1024; o <<= 1) {
    int a[4];
#pragma unroll
    for (int j = 0; j < 4; j++) {
      int i = t + j * 256;
      a[j] = (i >= o) ? sc[i - o] : 0;
    }
    __syncthreads();
#pragma unroll
    for (int j = 0; j < 4; j++) sc[t + j * 256] += a[j];
    __syncthreads();
  }
  int gbase = bbase[b];
#pragma unroll
  for (int j = 0; j < 4; j++) {
    int i = t + j * 256;
    if (i < w) {
      int c0 = gbase + sc[i] - cnt[i];  // exclusive offset for dst lo+i
      row_ptr[lo + i] = c0;
      cnt[i] = c0;  // reuse as global cursor
    }
  }
  __syncthreads();
  for (int p = t; p < m; p += 256) {
    uint2 v = S[p];
    int d = (int)(v.y & 0xFFFFFu);
    int pos = atomicAdd(&cnt[d - lo], 1);
    csr2[pos] = v;
  }
}

// Edge scores + exp, walking edges in dst-sorted order (csr2): head gathers
// stream monotonically through each proj plane, tail gathers hit LLC behind
// the stream. ex is written IN PLACE over csr2[e].y. 8 lanes per edge
// (128B rows), 4 edge-batches per wave. proj is PLANE-major [k][N][64].
__global__ __launch_bounds__(256) void k_logits(const short* __restrict__ ps,
                                                const float* __restrict__ rel_emb,
                                                uint2* csr2, int nE, int n_ent) {
  int t = threadIdx.x;
  int lane = t & 63;
  int sub = lane >> 3;        // edge slot within wave (0..7)
  int c8 = (lane & 7) * 8;    // component group base
  int e0 = (blockIdx.x * 4 + (t >> 6)) * 32;
  if (e0 >= nE) return;
  int ku[4];
  short8 tl[4], hd[4];
#pragma unroll
  for (int u = 0; u < 4; u++) {
    int e = e0 + u * 8 + sub;
    int ee = e < nE ? e : nE - 1;
    uint2 c = csr2[ee];
    int s = (int)c.x;
    int d = (int)(c.y & 0xFFFFFu);
    int k = (int)(c.y >> 20);
    ku[u] = k;
    const size_t plane = (size_t)k * n_ent;
    tl[u] = *(const short8*)(ps + (plane + s) * 64 + c8);
    hd[u] = *(const short8*)(ps + (plane + d) * 64 + c8);
  }
  float v[4];
#pragma unroll
  for (int u = 0; u < 4; u++) {
    const float* rp = rel_emb + ku[u] * 64 + c8;
    float4 r0 = *(const float4*)rp;
    float4 r1 = *(const float4*)(rp + 4);
    float rr[8] = {r0.x, r0.y, r0.z, r0.w, r1.x, r1.y, r1.z, r1.w};
    float vv = 0.f;
#pragma unroll
    for (int q = 0; q < 8; q++) {
      float x = bf2f(hd[u][q]) + rr[q];
      // tanh(x) = 1 - 2/(exp2(2*log2e*x)+1); v_exp + v_rcp, no IEEE div
      float tt = __builtin_amdgcn_exp2f(x * (2.f * LOG2E));
      float r = __builtin_amdgcn_rcpf(tt + 1.f);
      float th = fmaf(-2.f, r, 1.f);
      vv = fmaf(bf2f(tl[u][q]), th, vv);
    }
    vv += __shfl_xor(vv, 1);
    vv += __shfl_xor(vv, 2);
    vv += __shfl_xor(vv, 4);
    v[u] = __builtin_amdgcn_exp2f(vv * LOG2E);  // e^vv; logits bounded
  }
  // One edge per lane (32 lanes): edge (u=lane&7, sub). v is uniform across
  // each sub-group of 8 lanes, so the select chain is safe.
  int uu = lane & 7;
  if (uu < 4) {
    float myv = v[0];
    if (uu == 1) myv = v[1];
    if (uu == 2) myv = v[2];
    if (uu == 3) myv = v[3];
    int e = e0 + uu * 8 + sub;
    if (e < nE) csr2[e].y = __float_as_uint(myv);
  }
}

// h_n[n,:] = (sum_j ex_j * x[src_j,:]) / den. Wave per node, lane = col.
// ONE coalesced csr load (lane=entry), shfl broadcast, den wave-reduced.
// Masked 8-wide batches: lanes >= deg hold exv=0 so OOR shfl sources add 0.
__global__ __launch_bounds__(256) void k_agg(const short* __restrict__ xh,
                                             const int* __restrict__ row_ptr,
                                             const uint2* __restrict__ csr,
                                             float* __restrict__ hn, int n_ent) {
  int wave = threadIdx.x >> 6, lane = threadIdx.x & 63;
  int n = blockIdx.x * 4 + wave;
  if (n >= n_ent) return;
  int jb = row_ptr[n], je = row_ptr[n + 1];
  int deg = je - jb;
  if (deg == 0) {
    hn[(size_t)n * 64 + lane] = 0.f;  // no edges: reference h = 0
    return;
  }
  uint2 c = (lane < deg) ? csr[jb + lane] : make_uint2(0u, 0u);
  int sidx = (int)c.x;
  float exv = (lane < deg) ? __uint_as_float(c.y) : 0.f;
  float den = exv;
#pragma unroll
  for (int o = 32; o; o >>= 1) den += __shfl_xor(den, o);
  int m = deg < 64 ? deg : 64;
  float acc = 0.f;
  for (int j = 0; j < m; j += 8) {
    int s0 = __shfl(sidx, j), s1 = __shfl(sidx, j + 1);
    int s2 = __shfl(sidx, j + 2), s3 = __shfl(sidx, j + 3);
    int s4 = __shfl(sidx, j + 4), s5 = __shfl(sidx, j + 5);
    int s6 = __shfl(sidx, j + 6), s7 = __shfl(sidx, j + 7);
    float e0 = __shfl(exv, j), e1 = __shfl(exv, j + 1);
    float e2 = __shfl(exv, j + 2), e3 = __shfl(exv, j + 3);
    float e4 = __shfl(exv, j + 4), e5 = __shfl(exv, j + 5);
    float e6 = __shfl(exv, j + 6), e7 = __shfl(exv, j + 7);
    short g0 = xh[(size_t)s0 * 64 + lane];
    short g1 = xh[(size_t)s1 * 64 + lane];
    short g2 = xh[(size_t)s2 * 64 + lane];
    short g3 = xh[(size_t)s3 * 64 + lane];
    short g4 = xh[(size_t)s4 * 64 + lane];
    short g5 = xh[(size_t)s5 * 64 + lane];
    short g6 = xh[(size_t)s6 * 64 + lane];
    short g7 = xh[(size_t)s7 * 64 + lane];
    acc = fmaf(e0, bf2f(g0), acc); acc = fmaf(e1, bf2f(g1), acc);
    acc = fmaf(e2, bf2f(g2), acc); acc = fmaf(e3, bf2f(g3), acc);
    acc = fmaf(e4, bf2f(g4), acc); acc = fmaf(e5, bf2f(g5), acc);
    acc = fmaf(e6, bf2f(g6), acc); acc = fmaf(e7, bf2f(g7), acc);
  }
  if (deg > 64) {  // rare (E/N ~ 10); broadcast loads, den stays uniform
    for (int jj = jb + 64; jj < je; jj++) {
      uint2 cc = csr[jj];
      float ee = __uint_as_float(cc.y);
      den += ee;
      acc = fmaf(ee, bf2f(xh[(size_t)cc.x * 64 + lane]), acc);
    }
  }
  hn[(size_t)n * 64 + lane] = acc / den;
}

// y = lrelu((x+h)W1^T+b1) + lrelu((x*h)W2^T+b2) via MFMA.
// Split-bf16 GEMM (3 terms) keeps f32-level accuracy. Block = 4 waves x 32
// nodes = 128 nodes. Weights (hi/lo) staged once to LDS, stride 72 shorts
// (16B-aligned rows, bank-uniform ds_read_b128). A fragments built from f32
// x/hn loads. FIRST also emits x0 passthrough, x1 f32 and x1 bf16.
template <int OD, bool FIRST>
__global__ __launch_bounds__(256) void k_upmfma(const float* __restrict__ x,
                                                const float* __restrict__ hn,
                                                const short* __restrict__ g1h,
                                                const short* __restrict__ g1l,
                                                const short* __restrict__ g2h,
                                                const short* __restrict__ g2l,
                                                const float* __restrict__ b1,
                                                const float* __restrict__ b2,
                                                float* __restrict__ out,
                                                float* __restrict__ x_next,
                                                short* __restrict__ xh_next,
                                                int n_ent) {
  constexpr int NT = OD / 16;
  __shared__ short w1h[OD * 72], w1l[OD * 72], w2h[OD * 72], w2l[OD * 72];
  int t = threadIdx.x;
  for (int i = t; i < OD * 16; i += 256) {  // uint2 = 4 shorts per slot
    int o = i >> 4, dq = (i & 15) * 4;
    *(uint2*)(w1h + o * 72 + dq) = *(const uint2*)(g1h + o * 64 + dq);
    *(uint2*)(w1l + o * 72 + dq) = *(const uint2*)(g1l + o * 64 + dq);
    *(uint2*)(w2h + o * 72 + dq) = *(const uint2*)(g2h + o * 64 + dq);
    *(uint2*)(w2l + o * 72 + dq) = *(const uint2*)(g2l + o * 64 + dq);
  }
  int wave = t >> 6, lane = t & 63;
  int quad = lane >> 4, l16 = lane & 15;
  int m0 = blockIdx.x * 128 + wave * 32;
  float4v accA[2][NT], accM[2][NT];
#pragma unroll
  for (int mt = 0; mt < 2; mt++)
#pragma unroll
    for (int nt = 0; nt < NT; nt++) {
      accA[mt][nt] = (float4v){0.f, 0.f, 0.f, 0.f};
      accM[mt][nt] = (float4v){0.f, 0.f, 0.f, 0.f};
    }
  __syncthreads();
#pragma unroll
  for (int kc = 0; kc < 2; kc++) {
    short8 ah_add[2], al_add[2], ah_mul[2], al_mul[2];
#pragma unroll
    for (int mt = 0; mt < 2; mt++) {
      int row = m0 + mt * 16 + l16;
      int rr = row < n_ent ? row : 0;  // clamp; clamped rows never stored
      const float* xp = x + (size_t)rr * 64 + kc * 32 + quad * 8;
      const float* hp = hn + (size_t)rr * 64 + kc * 32 + quad * 8;
      float4 xa = *(const float4*)xp;
      float4 xb = *(const float4*)(xp + 4);
      float4 ha = *(const float4*)hp;
      float4 hb = *(const float4*)(hp + 4);
      if (FIRST && row < n_ent) {  // x0 passthrough from the same loads
        *(float4*)(out + (size_t)row * 160 + kc * 32 + quad * 8) = xa;
        *(float4*)(out + (size_t)row * 160 + kc * 32 + quad * 8 + 4) = xb;
      }
      float xs[8] = {xa.x, xa.y, xa.z, xa.w, xb.x, xb.y, xb.z, xb.w};
      float hs[8] = {ha.x, ha.y, ha.z, ha.w, hb.x, hb.y, hb.z, hb.w};
#pragma unroll
      for (int q = 0; q < 8; q++) {
        float s = xs[q] + hs[q];
        short shi = f2bf(s);
        ah_add[mt][q] = shi;
        al_add[mt][q] = f2bf(s - bf2f(shi));
        float p = xs[q] * hs[q];
        short phi = f2bf(p);
        ah_mul[mt][q] = phi;
        al_mul[mt][q] = f2bf(p - bf2f(phi));
      }
    }
#pragma unroll
    for (int nt = 0; nt < NT; nt++) {
      int boff = (nt * 16 + l16) * 72 + kc * 32 + quad * 8;
      short8 b1h = *(const short8*)(w1h + boff);
      short8 b1l = *(const short8*)(w1l + boff);
      short8 b2h = *(const short8*)(w2h + boff);
      short8 b2l = *(const short8*)(w2l + boff);
#pragma unroll
      for (int mt = 0; mt < 2; mt++) {
        accA[mt][nt] = __builtin_amdgcn_mfma_f32_16x16x32_bf16(
            ah_add[mt], b1h, accA[mt][nt], 0, 0, 0);
        accA[mt][nt] = __builtin_amdgcn_mfma_f32_16x16x32_bf16(
            al_add[mt], b1h, accA[mt][nt], 0, 0, 0);
        accA[mt][nt] = __builtin_amdgcn_mfma_f32_16x16x32_bf16(
            ah_add[mt], b1l, accA[mt][nt], 0, 0, 0);
        accM[mt][nt] = __builtin_amdgcn_mfma_f32_16x16x32_bf16(
            ah_mul[mt], b2h, accM[mt][nt], 0, 0, 0);
        accM[mt][nt] = __builtin_amdgcn_mfma_f32_16x16x32_bf16(
            al_mul[mt], b2h, accM[mt][nt], 0, 0, 0);
        accM[mt][nt] = __builtin_amdgcn_mfma_f32_16x16x32_bf16(
            ah_mul[mt], b2l, accM[mt][nt], 0, 0, 0);
      }
    }
  }
  // C layout: col = nt*16+l16, row = mt*16 + quad*4 + r
#pragma unroll
  for (int nt = 0; nt < NT; nt++) {
    int col = nt * 16 + l16;
    float bb1 = b1[col], bb2 = b2[col];
#pragma unroll
    for (int mt = 0; mt < 2; mt++) {
#pragma unroll
      for (int r = 0; r < 4; r++) {
        int row = m0 + mt * 16 + quad * 4 + r;
        float aa = accA[mt][nt][r] + bb1;
        float mm = accM[mt][nt][r] + bb2;
        aa = aa > 0.f ? aa : 0.01f * aa;
        mm = mm > 0.f ? mm : 0.01f * mm;
        float y = aa + mm;
        if constexpr (FIRST) {
          float yn = __shfl_xor(y, 1);  // partner col^1, same row (quad equal)
          if (row < n_ent) {
            out[(size_t)row * 160 + 64 + col] = y;
            x_next[(size_t)row * 64 + col] = y;
            if ((lane & 1) == 0) {
              unsigned pk = (unsigned)(unsigned short)f2bf(y) |
                            ((unsigned)(unsigned short)f2bf(yn) << 16);
              *(unsigned*)(xh_next + (size_t)row * 64 + col) = pk;
            }
          }
        } else {
          if (row < n_ent) out[(size_t)row * 160 + 128 + col] = y;
        }
      }
    }
  }
}

extern "C" void kernel_launch(void* const* d_in, const int* in_sizes, int n_in,
                              void* d_out, int out_size, void* d_ws, size_t ws_size,
                              hipStream_t stream) {
  const float* emb = (const float*)d_in[0];
  const float* rel = (const float*)d_in[1];
  const float* Wr = (const float*)d_in[2];
  const float* W10w = (const float*)d_in[3];
  const float* W10b = (const float*)d_in[4];
  const float* W20w = (const float*)d_in[5];
  const float* W20b = (const float*)d_in[6];
  const float* W11w = (const float*)d_in[7];
  const float* W11b = (const float*)d_in[8];
  const float* W21w = (const float*)d_in[9];
  const float* W21b = (const float*)d_in[10];
  const int* src = (const int*)d_in[11];
  const int* dst = (const int*)d_in[12];
  const int* et = (const int*)d_in[13];
  int N = in_sizes[0] / 64;
  int E = in_sizes[11];
  float* out = (float*)d_out;

  int bsh = 9;
  while (((N + (1 << bsh) - 1) >> bsh) > 256) bsh++;  // nbuck <= 256
  int nbuck = (N + (1 << bsh) - 1) >> bsh;
  int cap = ((E / nbuck) * 3 / 2 + 1024 + 255) / 256 * 256;  // ~50 sigma margin

  char* p = (char*)d_ws;
  auto alloc = [&](size_t bytes) -> char* {
    char* r = p;
    p += (bytes + 255) / 256 * 256;
    return r;
  };
  short* proj = (short*)alloc((size_t)N * 768 * 2);
  uint2* csr2 = (uint2*)alloc((size_t)E * 8);  // final CSR {src, dst|et} -> {src, ex}
  uint2* stg = (uint2*)alloc((size_t)nbuck * cap * 8);  // per-bucket staging
  int* row_ptr = (int*)alloc((size_t)(N + 1) * 4);
  int* bcur = (int*)alloc(1024);               // bucket staging cursors
  int* bbase = (int*)alloc(2048);              // bucket bases in CSR
  float* hn = (float*)alloc((size_t)N * 64 * 4);
  float* x1 = (float*)alloc((size_t)N * 64 * 4);
  short* emb_h = (short*)alloc(((size_t)N + 128) * 64 * 2);  // bf16 emb, padded
  short* x1h = (short*)alloc(((size_t)N + 128) * 64 * 2);    // bf16 x1
  short* Bt = (short*)alloc((size_t)12 * 4096 * 2);          // bf16 W_r^T
  short* w1h0 = (short*)alloc(4096 * 2);                     // layer-weight hi/lo
  short* w1l0 = (short*)alloc(4096 * 2);
  short* w2h0 = (short*)alloc(4096 * 2);
  short* w2l0 = (short*)alloc(4096 * 2);
  short* w1h1 = (short*)alloc(2048 * 2);
  short* w1l1 = (short*)alloc(2048 * 2);
  short* w2h1 = (short*)alloc(2048 * 2);
  short* w2l1 = (short*)alloc(2048 * 2);

  int n4 = N * 16;
  int nb_cvt = (n4 + 255) / 256;
  int nb1 = (E + 8191) / 8192;       // bsort1 blocks
  int nb_gemm = (N + 127) / 128;     // GEMM blocks (128 nodes each)
  int nb_tot = nb1 + nb_gemm;
  int K = nb_tot / nb1;              // every K-th block is bsort1
  if (K < 1) K = 1;

  hipMemsetAsync(bcur, 0, 1024, stream);
  k_prep<<<nb_cvt + 60, 256, 0, stream>>>(
      emb, emb_h, Wr, Bt, W10w, W20w, W11w, W21w,
      w1h0, w1l0, w2h0, w2l0, w1h1, w1l1, w2h1, w2l1, nb_cvt, n4);
  k_projb1<<<nb_tot, 256, 0, stream>>>(
      emb_h, Bt, proj, N, src, dst, et, bcur, stg, E, bsh, cap, nb1, K);
  k_bscan<<<1, 256, 0, stream>>>(bcur, bbase, row_ptr, nbuck, N, E);
  k_bsort2<<<nbuck, 256, 0, stream>>>(stg, bcur, bbase, row_ptr, csr2, N, bsh, cap);
  k_logits<<<(E + 127) / 128, 256, 0, stream>>>(proj, rel, csr2, E, N);
  k_agg<<<(N + 3) / 4, 256, 0, stream>>>(emb_h, row_ptr, csr2, hn, N);
  k_upmfma<64, true><<<(N + 127) / 128, 256, 0, stream>>>(
      emb, hn, w1h0, w1l0, w2h0, w2l0, W10b, W20b, out, x1, x1h, N);
  k_agg<<<(N + 3) / 4, 256, 0, stream>>>(x1h, row_ptr, csr2, hn, N);
  k_upmfma<32, false><<<(N + 127) / 128, 256, 0, stream>>>(
      x1, hn, w1h1, w1l1, w2h1, w2l1, W11b, W21b, out, nullptr, nullptr, N);
}